// Round 4
// baseline (252.546 us; speedup 1.0000x reference)
//
#include <hip/hip_runtime.h>
#include <hip/hip_bf16.h>

#define B_NUM 2
#define S_LEN 2048
#define E_DIM 1024
#define H_NUM 16
#define D_DIM 64
#define QKV_LD 3072

typedef __attribute__((ext_vector_type(8))) short bf16x8;
typedef __attribute__((ext_vector_type(8))) unsigned short u16x8;
typedef __attribute__((ext_vector_type(4))) unsigned short u16x4;
typedef __attribute__((ext_vector_type(4))) float f32x4;
typedef __attribute__((ext_vector_type(16))) float f32x16;
typedef __attribute__((ext_vector_type(2))) int i32x2;

static __device__ __forceinline__ unsigned short f2bf(float f) {
    union { float f; unsigned int u; } v; v.f = f;
    unsigned int r = v.u + 0x7fffu + ((v.u >> 16) & 1u);   // RNE
    return (unsigned short)(r >> 16);
}

static __device__ __forceinline__ unsigned cvtpk_bf16(float lo, float hi) {
    unsigned r;
    asm("v_cvt_pk_bf16_f32 %0, %1, %2" : "=v"(r) : "v"(lo), "v"(hi));
    return r;
}

// async global->LDS, 16B per lane; LDS dest = uniform base + lane*16
static __device__ __forceinline__ void gload16(const void* gsrc, void* ldst) {
    __builtin_amdgcn_global_load_lds(
        (const __attribute__((address_space(1))) unsigned int*)gsrc,
        (__attribute__((address_space(3))) unsigned int*)ldst, 16, 0, 0);
}

// ---------------------------------------------------------------------------
// fp32 -> bf16 bulk convert
// ---------------------------------------------------------------------------
__global__ __launch_bounds__(256)
void cvt_f32_bf16(const float* __restrict__ in, unsigned short* __restrict__ outp, int n4) {
    int i = blockIdx.x * blockDim.x + threadIdx.x;
    if (i < n4) {
        float4 f = ((const float4*)in)[i];
        u16x4 o = { f2bf(f.x), f2bf(f.y), f2bf(f.z), f2bf(f.w) };
        ((u16x4*)outp)[i] = o;
    }
}

// ---------------------------------------------------------------------------
// 128x128 bf16 MFMA GEMM, BK=64, 4 waves (each 64x64 = 4x4 16x16x32 frags).
// Staging via global_load_lds (linear LDS dest, pre-swizzled global source:
// content at LDS (row, blk16B) = global (row, blk ^ (row&7)) so swizzled
// frag reads are conflict-free). C = A * Bw^T, both K-contiguous.
// ---------------------------------------------------------------------------
template <bool OUT_BF16, bool QSCALE>
__global__ __launch_bounds__(256)
void gemm_bt_mfma128(const unsigned short* __restrict__ A,
                     const unsigned short* __restrict__ Bw,
                     void* __restrict__ Cv, int M, int N, int K) {
    __shared__ unsigned short As[128 * 64];
    __shared__ unsigned short Bs[128 * 64];
    char* const AsB = (char*)As;
    char* const BsB = (char*)Bs;
    const int tid  = threadIdx.x;
    const int lane = tid & 63;
    const int w    = tid >> 6;
    const int lg   = lane >> 4;
    const int lq   = lane & 15;
    const int bm = blockIdx.y * 128;
    const int bn = blockIdx.x * 128;
    const int wr = (w >> 1) * 64;
    const int wc = (w & 1) * 64;
    const int lrow8 = lane >> 3;               // sub-row within 8-row chunk
    const int gblk  = (lane & 7) ^ lrow8;      // pre-swizzled 16B column block

    f32x4 acc[4][4];
#pragma unroll
    for (int i = 0; i < 4; ++i)
#pragma unroll
        for (int j = 0; j < 4; ++j) acc[i][j] = (f32x4){0.f, 0.f, 0.f, 0.f};

    for (int k0 = 0; k0 < K; k0 += 64) {
        __syncthreads();
#pragma unroll
        for (int t = 0; t < 4; ++t) {
            const int c = w * 4 + t;           // chunk 0..15 (8 rows each)
            const int row = c * 8 + lrow8;
            gload16(A + (size_t)(bm + row) * K + k0 + gblk * 8, AsB + c * 1024);
            gload16(Bw + (size_t)(bn + row) * K + k0 + gblk * 8, BsB + c * 1024);
        }
        __syncthreads();

        bf16x8 af[4][2], bfr[4][2];
#pragma unroll
        for (int rt = 0; rt < 4; ++rt) {
            const int row = wr + rt * 16 + lq;
            const int sz = (row & 7) << 4;
            af[rt][0] = *(const bf16x8*)(AsB + row * 128 + ((lg * 16)      ^ sz));
            af[rt][1] = *(const bf16x8*)(AsB + row * 128 + ((64 + lg * 16) ^ sz));
        }
#pragma unroll
        for (int ct = 0; ct < 4; ++ct) {
            const int row = wc + ct * 16 + lq;
            const int sz = (row & 7) << 4;
            bfr[ct][0] = *(const bf16x8*)(BsB + row * 128 + ((lg * 16)      ^ sz));
            bfr[ct][1] = *(const bf16x8*)(BsB + row * 128 + ((64 + lg * 16) ^ sz));
        }
#pragma unroll
        for (int rt = 0; rt < 4; ++rt)
#pragma unroll
            for (int ct = 0; ct < 4; ++ct) {
                acc[rt][ct] = __builtin_amdgcn_mfma_f32_16x16x32_bf16(af[rt][0], bfr[ct][0], acc[rt][ct], 0, 0, 0);
                acc[rt][ct] = __builtin_amdgcn_mfma_f32_16x16x32_bf16(af[rt][1], bfr[ct][1], acc[rt][ct], 0, 0, 0);
            }
    }

#pragma unroll
    for (int rt = 0; rt < 4; ++rt)
#pragma unroll
        for (int ct = 0; ct < 4; ++ct) {
            const int row = bm + wr + rt * 16 + lg * 4;
            const int col = bn + wc + ct * 16 + lq;
            float scale = 1.f;
            if constexpr (QSCALE) scale = ((col % 192) < 64) ? 0.125f : 1.f;
#pragma unroll
            for (int r = 0; r < 4; ++r) {
                float vv = acc[rt][ct][r] * scale;
                if constexpr (OUT_BF16)
                    ((unsigned short*)Cv)[(size_t)(row + r) * N + col] = f2bf(vv);
                else
                    ((float*)Cv)[(size_t)(row + r) * N + col] = vv;
            }
        }
}

// ---------------------------------------------------------------------------
// 64x64 bf16 MFMA GEMM (round-2 known-good; used for the output projection
// where the 128^2 grid would drop to 1 block/CU).
// ---------------------------------------------------------------------------
template <bool OUT_BF16, bool QSCALE>
__global__ __launch_bounds__(256)
void gemm_bt_mfma(const unsigned short* __restrict__ A,
                  const unsigned short* __restrict__ Bw,
                  void* __restrict__ Cv, int M, int N, int K) {
    __shared__ unsigned short As[64 * 64];
    __shared__ unsigned short Bs[64 * 64];
    char* const AsB = (char*)As;
    char* const BsB = (char*)Bs;
    const int tid  = threadIdx.x;
    const int lane = tid & 63;
    const int w    = tid >> 6;
    const int lg   = lane >> 4;
    const int lq   = lane & 15;
    const int bm = blockIdx.y * 64;
    const int bn = blockIdx.x * 64;
    const int wr = (w >> 1) * 32;
    const int wc = (w & 1) * 32;
    const int sr = tid >> 2;
    const int sc = (tid & 3) * 16;
    const int swzS = (sr & 7) << 4;

    f32x4 acc[2][2];
#pragma unroll
    for (int i = 0; i < 2; ++i)
#pragma unroll
        for (int j = 0; j < 2; ++j) acc[i][j] = (f32x4){0.f, 0.f, 0.f, 0.f};

    const unsigned short* ap = A  + (size_t)(bm + sr) * K + sc;
    const unsigned short* bp = Bw + (size_t)(bn + sr) * K + sc;

    for (int k0 = 0; k0 < K; k0 += 64) {
        __syncthreads();
        u16x8 av0 = *(const u16x8*)(ap + k0);
        u16x8 av1 = *(const u16x8*)(ap + k0 + 8);
        u16x8 bv0 = *(const u16x8*)(bp + k0);
        u16x8 bv1 = *(const u16x8*)(bp + k0 + 8);
        *(u16x8*)(AsB + sr * 128 + ((sc * 2)      ^ swzS)) = av0;
        *(u16x8*)(AsB + sr * 128 + ((sc * 2 + 16) ^ swzS)) = av1;
        *(u16x8*)(BsB + sr * 128 + ((sc * 2)      ^ swzS)) = bv0;
        *(u16x8*)(BsB + sr * 128 + ((sc * 2 + 16) ^ swzS)) = bv1;
        __syncthreads();

        bf16x8 af[2][2], bfr[2][2];
#pragma unroll
        for (int rt = 0; rt < 2; ++rt) {
            const int row = wr + rt * 16 + lq;
            const int sz = (row & 7) << 4;
            af[rt][0] = *(const bf16x8*)(AsB + row * 128 + ((lg * 16)      ^ sz));
            af[rt][1] = *(const bf16x8*)(AsB + row * 128 + ((64 + lg * 16) ^ sz));
        }
#pragma unroll
        for (int ct = 0; ct < 2; ++ct) {
            const int row = wc + ct * 16 + lq;
            const int sz = (row & 7) << 4;
            bfr[ct][0] = *(const bf16x8*)(BsB + row * 128 + ((lg * 16)      ^ sz));
            bfr[ct][1] = *(const bf16x8*)(BsB + row * 128 + ((64 + lg * 16) ^ sz));
        }
#pragma unroll
        for (int rt = 0; rt < 2; ++rt)
#pragma unroll
            for (int ct = 0; ct < 2; ++ct) {
                acc[rt][ct] = __builtin_amdgcn_mfma_f32_16x16x32_bf16(af[rt][0], bfr[ct][0], acc[rt][ct], 0, 0, 0);
                acc[rt][ct] = __builtin_amdgcn_mfma_f32_16x16x32_bf16(af[rt][1], bfr[ct][1], acc[rt][ct], 0, 0, 0);
            }
    }

#pragma unroll
    for (int rt = 0; rt < 2; ++rt)
#pragma unroll
        for (int ct = 0; ct < 2; ++ct) {
            const int row = bm + wr + rt * 16 + lg * 4;
            const int col = bn + wc + ct * 16 + lq;
            float scale = 1.f;
            if constexpr (QSCALE) scale = ((col % 192) < 64) ? 0.125f : 1.f;
#pragma unroll
            for (int r = 0; r < 4; ++r) {
                float vv = acc[rt][ct][r] * scale;
                if constexpr (OUT_BF16)
                    ((unsigned short*)Cv)[(size_t)(row + r) * N + col] = f2bf(vv);
                else
                    ((float*)Cv)[(size_t)(row + r) * N + col] = vv;
            }
        }
}

// ---------------------------------------------------------------------------
// Flash attention, swapped-QK^T 32x32x16, KV-SPLIT: 512 threads = 8 waves =
// 2 groups x 4 waves. Group g handles keys [g*1024, g*1024+1024) in 16 tiles
// of 64 over its own K/V LDS buffers; the two partial (m,l,O) states are
// merged through LDS at the end (group 0 writes final output).
// K staged via global_load_lds with pre-swizzled source; V staged transposed.
// Online softmax with defer-max (THR=8).
// ---------------------------------------------------------------------------
__global__ __launch_bounds__(512, 4)
void attn_mfma32_split(const unsigned short* __restrict__ qkv, const int* __restrict__ mask,
                       unsigned short* __restrict__ vout) {
    __shared__ __align__(16) char pool[32768];          // Ks[2] 16KB | Vt[2] 16KB; reused as merge-O
    __shared__ __align__(16) float MskF[2][64];
    __shared__ float Ml[4][64];

    const int tid  = threadIdx.x;
    const int lane = tid & 63;
    const int wid  = tid >> 6;     // 0..7
    const int g    = wid >> 2;     // kv group
    const int w    = wid & 3;      // wave within group
    const int tg   = tid & 255;    // thread within group
    const int ln   = lane & 31;
    const int hi   = lane >> 5;
    const int q0 = blockIdx.x * 128;
    const int h  = blockIdx.y;
    const int b  = blockIdx.z;
    const size_t baseBH = (size_t)b * S_LEN * QKV_LD + (size_t)h * (3 * D_DIM);
    const unsigned short* const kv = qkv + baseBH;

    char* const KsB = pool + g * 8192;
    char* const VtB = pool + 16384 + g * 8192;

    // Q as B-frags (pre-scaled by 0.125): qf[kk] = Q[q=ln][d=kk*16+hi*8+j]
    bf16x8 qf[4];
    {
        const unsigned short* qp = kv + (size_t)(q0 + w * 32 + ln) * QKV_LD + hi * 8;
#pragma unroll
        for (int kk = 0; kk < 4; ++kk)
            qf[kk] = *(const bf16x8*)(qp + kk * 16);
    }

    f32x16 accO[2];
#pragma unroll
    for (int dt = 0; dt < 2; ++dt)
#pragma unroll
        for (int r = 0; r < 16; ++r) accO[dt][r] = 0.f;
    float mrun = 0.f, lrow = 0.f;   // bias -3e4 -> masked p == 0 under m>=0

    const int lrow8 = lane >> 3;
    const int gblk  = (lane & 7) ^ lrow8;   // pre-swizzled 16B block for K stage
    const int vkb = (tg & 15) * 4;          // V staging key base
    const int vdb = (tg >> 4) * 4;          // V staging d base

    const int kvbase = g * 1024;
    for (int it = 0; it < 16; ++it) {
        const int kv0 = kvbase + it * 64;
        __syncthreads();
        {   // stage K via global_load_lds (linear dest, pre-swizzled source)
#pragma unroll
            for (int t = 0; t < 2; ++t) {
                const int c = w * 2 + t;            // chunk 0..7 (8 rows each)
                const int row = c * 8 + lrow8;
                gload16(kv + (size_t)(kv0 + row) * QKV_LD + D_DIM + gblk * 8,
                        KsB + c * 1024);
            }
        }
        {   // stage V transposed [d][key], swizzled
            u16x4 vr[4];
#pragma unroll
            for (int i = 0; i < 4; ++i)
                vr[i] = *(const u16x4*)(kv + (size_t)(kv0 + vkb + i) * QKV_LD + 2 * D_DIM + vdb);
#pragma unroll
            for (int j = 0; j < 4; ++j) {
                u16x4 o = { vr[0][j], vr[1][j], vr[2][j], vr[3][j] };
                const int row = vdb + j;
                *(u16x4*)(VtB + row * 128 + ((vkb * 2) ^ ((row & 7) << 4))) = o;
            }
        }
        if (tg < 64) MskF[g][tg] = (mask[b * S_LEN + kv0 + tg] != 0) ? 0.f : -30000.f;
        __syncthreads();

        // ---- S^T = K Q^T + bias. key = (r&3)+8*(r>>2)+4*hi+32*ks, q = ln ----
        f32x16 s[2];
#pragma unroll
        for (int ks = 0; ks < 2; ++ks)
#pragma unroll
            for (int m = 0; m < 4; ++m) {
                f32x4 b4 = *(const f32x4*)(&MskF[g][ks * 32 + m * 8 + hi * 4]);
#pragma unroll
                for (int i = 0; i < 4; ++i) s[ks][m * 4 + i] = b4[i];
            }
#pragma unroll
        for (int ks = 0; ks < 2; ++ks) {
            const int krow = ks * 32 + ln;
            const int swz = (ln & 7) << 4;
#pragma unroll
            for (int kk = 0; kk < 4; ++kk) {
                bf16x8 kf = *(const bf16x8*)(KsB + krow * 128 + (((kk * 16 + hi * 8) * 2) ^ swz));
                s[ks] = __builtin_amdgcn_mfma_f32_32x32x16_bf16(kf, qf[kk], s[ks], 0, 0, 0);
            }
        }

        // ---- online softmax with defer-max ----
        float tm = -3.4e38f;
#pragma unroll
        for (int ks = 0; ks < 2; ++ks)
#pragma unroll
            for (int r = 0; r < 16; ++r) tm = fmaxf(tm, s[ks][r]);
        {
            i32x2 rr = __builtin_amdgcn_permlane32_swap(__float_as_int(tm), __float_as_int(tm), false, false);
            tm = fmaxf(__int_as_float(rr[0]), __int_as_float(rr[1]));
        }
        float rsum = 0.f;
        if (__all(tm <= mrun + 8.f)) {          // defer: keep old max, skip rescale
#pragma unroll
            for (int ks = 0; ks < 2; ++ks)
#pragma unroll
                for (int r = 0; r < 16; ++r) {
                    float p = __expf(s[ks][r] - mrun);
                    s[ks][r] = p;
                    rsum += p;
                }
            i32x2 rr = __builtin_amdgcn_permlane32_swap(__float_as_int(rsum), __float_as_int(rsum), false, false);
            lrow += __int_as_float(rr[0]) + __int_as_float(rr[1]);
        } else {
            const float mnew = fmaxf(mrun, tm);
            const float fsc = __expf(mrun - mnew);
#pragma unroll
            for (int ks = 0; ks < 2; ++ks)
#pragma unroll
                for (int r = 0; r < 16; ++r) {
                    float p = __expf(s[ks][r] - mnew);
                    s[ks][r] = p;
                    rsum += p;
                }
            i32x2 rr = __builtin_amdgcn_permlane32_swap(__float_as_int(rsum), __float_as_int(rsum), false, false);
            lrow = lrow * fsc + __int_as_float(rr[0]) + __int_as_float(rr[1]);
            mrun = mnew;
#pragma unroll
            for (int dt = 0; dt < 2; ++dt)
#pragma unroll
                for (int r = 0; r < 16; ++r) accO[dt][r] *= fsc;
        }

        // ---- assemble P^T B-frags in-register ----
        bf16x8 pb[4];
#pragma unroll
        for (int ks = 0; ks < 2; ++ks) {
            unsigned wA[4], wB[4];
#pragma unroll
            for (int m = 0; m < 4; ++m) {
                wA[m] = cvtpk_bf16(s[ks][4 * m + 0], s[ks][4 * m + 1]);
                wB[m] = cvtpk_bf16(s[ks][4 * m + 2], s[ks][4 * m + 3]);
            }
#pragma unroll
            for (int t = 0; t < 2; ++t) {
                i32x2 ra = __builtin_amdgcn_permlane32_swap((int)wA[2 * t], (int)wA[2 * t + 1], false, false);
                i32x2 rb = __builtin_amdgcn_permlane32_swap((int)wB[2 * t], (int)wB[2 * t + 1], false, false);
                union { unsigned u[4]; bf16x8 v; } uu;
                uu.u[0] = (unsigned)ra[0];
                uu.u[1] = (unsigned)rb[0];
                uu.u[2] = (unsigned)ra[1];
                uu.u[3] = (unsigned)rb[1];
                pb[ks * 2 + t] = uu.v;
            }
        }

        // ---- O^T += V^T P^T ----
#pragma unroll
        for (int dt = 0; dt < 2; ++dt) {
            const int drow = dt * 32 + ln;
            const int swz = (ln & 7) << 4;
#pragma unroll
            for (int n = 0; n < 4; ++n) {
                bf16x8 va = *(const bf16x8*)(VtB + drow * 128 + (((n * 16 + hi * 8) * 2) ^ swz));
                accO[dt] = __builtin_amdgcn_mfma_f32_32x32x16_bf16(va, pb[n], accO[dt], 0, 0, 0);
            }
        }
    }

    // ---- merge the two KV-halves through LDS; group 0 writes output ----
    __syncthreads();
    if (g == 1) {
        float* region = (float*)(pool + w * 8192);   // [d=64][q=32] fp32
#pragma unroll
        for (int dt = 0; dt < 2; ++dt)
#pragma unroll
            for (int m = 0; m < 4; ++m)
#pragma unroll
                for (int i = 0; i < 4; ++i)
                    region[(dt * 32 + 8 * m + 4 * hi + i) * 32 + ln] = accO[dt][4 * m + i];
        if (hi == 0) { Ml[w][ln] = mrun; Ml[w][32 + ln] = lrow; }
    }
    __syncthreads();
    if (g == 0) {
        const float* region = (const float*)(pool + w * 8192);
        const float m2 = Ml[w][ln];
        const float l2 = Ml[w][32 + ln];
        const float mm = fmaxf(mrun, m2);
        const float f1 = __expf(mrun - mm);
        const float f2 = __expf(m2 - mm);
        const float inv = 1.f / (lrow * f1 + l2 * f2);
        unsigned short* op = vout + (size_t)(b * S_LEN + q0 + w * 32 + ln) * E_DIM + h * D_DIM;
#pragma unroll
        for (int dt = 0; dt < 2; ++dt)
#pragma unroll
            for (int m = 0; m < 4; ++m) {
                u16x4 o;
#pragma unroll
                for (int i = 0; i < 4; ++i) {
                    float vv = accO[dt][4 * m + i] * f1
                             + region[(dt * 32 + 8 * m + 4 * hi + i) * 32 + ln] * f2;
                    o[i] = f2bf(vv * inv);
                }
                *(u16x4*)(op + dt * 32 + m * 8 + hi * 4) = o;
            }
    }
}

// ---------------------------------------------------------------------------
extern "C" void kernel_launch(void* const* d_in, const int* in_sizes, int n_in,
                              void* d_out, int out_size, void* d_ws, size_t ws_size,
                              hipStream_t stream) {
    const float* x      = (const float*)d_in[0];
    const int*   mask   = (const int*)d_in[1];
    const float* w_qkv  = (const float*)d_in[2];
    const float* w_o    = (const float*)d_in[3];
    float*       out    = (float*)d_out;

    const int M = B_NUM * S_LEN;     // 4096
    unsigned short* qkvb = (unsigned short*)d_ws;                    // M x 3E
    unsigned short* vbuf = qkvb + (size_t)M * 3 * E_DIM;             // M x E
    unsigned short* xb   = vbuf + (size_t)M * E_DIM;                 // M x E
    unsigned short* wqb  = xb   + (size_t)M * E_DIM;                 // 3E x E
    unsigned short* wob  = wqb  + (size_t)3 * E_DIM * E_DIM;         // E x E

    dim3 blk(256);
    {
        int n4;
        n4 = M * E_DIM / 4;
        cvt_f32_bf16<<<dim3((n4 + 255) / 256), blk, 0, stream>>>(x, xb, n4);
        n4 = 3 * E_DIM * E_DIM / 4;
        cvt_f32_bf16<<<dim3((n4 + 255) / 256), blk, 0, stream>>>(w_qkv, wqb, n4);
        n4 = E_DIM * E_DIM / 4;
        cvt_f32_bf16<<<dim3((n4 + 255) / 256), blk, 0, stream>>>(w_o, wob, n4);
    }

    // QKV projection (q columns pre-scaled by 0.125), bf16 out, 128^2 tile
    gemm_bt_mfma128<true, true><<<dim3(3 * E_DIM / 128, M / 128), blk, 0, stream>>>(
        xb, wqb, qkvb, M, 3 * E_DIM, E_DIM);

    // flash attention (KV-split, 8 waves)
    attn_mfma32_split<<<dim3(S_LEN / 128, H_NUM, B_NUM), dim3(512), 0, stream>>>(
        qkvb, mask, vbuf);

    // output projection, fp32 out, 64^2 tile (grid 1024)
    gemm_bt_mfma<false, false><<<dim3(E_DIM / 64, M / 64), blk, 0, stream>>>(
        vbuf, wob, out, M, E_DIM, E_DIM);
}

// Round 5
// 152.074 us; speedup vs baseline: 1.6607x; 1.6607x over previous
//
#include <hip/hip_runtime.h>
#include <hip/hip_bf16.h>

#define B_NUM 2
#define S_LEN 2048
#define E_DIM 1024
#define H_NUM 16
#define D_DIM 64
#define QKV_LD 3072

typedef __attribute__((ext_vector_type(8))) short bf16x8;
typedef __attribute__((ext_vector_type(8))) unsigned short u16x8;
typedef __attribute__((ext_vector_type(4))) unsigned short u16x4;
typedef __attribute__((ext_vector_type(4))) float f32x4;
typedef __attribute__((ext_vector_type(16))) float f32x16;
typedef __attribute__((ext_vector_type(2))) int i32x2;

static __device__ __forceinline__ unsigned short f2bf(float f) {
    union { float f; unsigned int u; } v; v.f = f;
    unsigned int r = v.u + 0x7fffu + ((v.u >> 16) & 1u);   // RNE
    return (unsigned short)(r >> 16);
}

static __device__ __forceinline__ float bf2f(unsigned short u) {
    union { unsigned int u; float f; } v; v.u = ((unsigned int)u) << 16;
    return v.f;
}

static __device__ __forceinline__ unsigned cvtpk_bf16(float lo, float hi) {
    unsigned r;
    asm("v_cvt_pk_bf16_f32 %0, %1, %2" : "=v"(r) : "v"(lo), "v"(hi));
    return r;
}

// async global->LDS, 16B per lane; LDS dest = uniform base + lane*16
static __device__ __forceinline__ void gload16(const void* gsrc, void* ldst) {
    __builtin_amdgcn_global_load_lds(
        (const __attribute__((address_space(1))) unsigned int*)gsrc,
        (__attribute__((address_space(3))) unsigned int*)ldst, 16, 0, 0);
}

// ---------------------------------------------------------------------------
// fp32 -> bf16 bulk convert
// ---------------------------------------------------------------------------
__global__ __launch_bounds__(256)
void cvt_f32_bf16(const float* __restrict__ in, unsigned short* __restrict__ outp, int n4) {
    int i = blockIdx.x * blockDim.x + threadIdx.x;
    if (i < n4) {
        float4 f = ((const float4*)in)[i];
        u16x4 o = { f2bf(f.x), f2bf(f.y), f2bf(f.z), f2bf(f.w) };
        ((u16x4*)outp)[i] = o;
    }
}

// ---------------------------------------------------------------------------
// 128x128 bf16 MFMA GEMM, BK=64, 4 waves (each 64x64 = 4x4 16x16x32 frags).
// Staging via global_load_lds, pre-swizzled global source. (round-4, passed)
// ---------------------------------------------------------------------------
template <bool OUT_BF16, bool QSCALE>
__global__ __launch_bounds__(256)
void gemm_bt_mfma128(const unsigned short* __restrict__ A,
                     const unsigned short* __restrict__ Bw,
                     void* __restrict__ Cv, int M, int N, int K) {
    __shared__ unsigned short As[128 * 64];
    __shared__ unsigned short Bs[128 * 64];
    char* const AsB = (char*)As;
    char* const BsB = (char*)Bs;
    const int tid  = threadIdx.x;
    const int lane = tid & 63;
    const int w    = tid >> 6;
    const int lg   = lane >> 4;
    const int lq   = lane & 15;
    const int bm = blockIdx.y * 128;
    const int bn = blockIdx.x * 128;
    const int wr = (w >> 1) * 64;
    const int wc = (w & 1) * 64;
    const int lrow8 = lane >> 3;
    const int gblk  = (lane & 7) ^ lrow8;

    f32x4 acc[4][4];
#pragma unroll
    for (int i = 0; i < 4; ++i)
#pragma unroll
        for (int j = 0; j < 4; ++j) acc[i][j] = (f32x4){0.f, 0.f, 0.f, 0.f};

    for (int k0 = 0; k0 < K; k0 += 64) {
        __syncthreads();
#pragma unroll
        for (int t = 0; t < 4; ++t) {
            const int c = w * 4 + t;
            const int row = c * 8 + lrow8;
            gload16(A + (size_t)(bm + row) * K + k0 + gblk * 8, AsB + c * 1024);
            gload16(Bw + (size_t)(bn + row) * K + k0 + gblk * 8, BsB + c * 1024);
        }
        __syncthreads();

        bf16x8 af[4][2], bfr[4][2];
#pragma unroll
        for (int rt = 0; rt < 4; ++rt) {
            const int row = wr + rt * 16 + lq;
            const int sz = (row & 7) << 4;
            af[rt][0] = *(const bf16x8*)(AsB + row * 128 + ((lg * 16)      ^ sz));
            af[rt][1] = *(const bf16x8*)(AsB + row * 128 + ((64 + lg * 16) ^ sz));
        }
#pragma unroll
        for (int ct = 0; ct < 4; ++ct) {
            const int row = wc + ct * 16 + lq;
            const int sz = (row & 7) << 4;
            bfr[ct][0] = *(const bf16x8*)(BsB + row * 128 + ((lg * 16)      ^ sz));
            bfr[ct][1] = *(const bf16x8*)(BsB + row * 128 + ((64 + lg * 16) ^ sz));
        }
#pragma unroll
        for (int rt = 0; rt < 4; ++rt)
#pragma unroll
            for (int ct = 0; ct < 4; ++ct) {
                acc[rt][ct] = __builtin_amdgcn_mfma_f32_16x16x32_bf16(af[rt][0], bfr[ct][0], acc[rt][ct], 0, 0, 0);
                acc[rt][ct] = __builtin_amdgcn_mfma_f32_16x16x32_bf16(af[rt][1], bfr[ct][1], acc[rt][ct], 0, 0, 0);
            }
    }

#pragma unroll
    for (int rt = 0; rt < 4; ++rt)
#pragma unroll
        for (int ct = 0; ct < 4; ++ct) {
            const int row = bm + wr + rt * 16 + lg * 4;
            const int col = bn + wc + ct * 16 + lq;
            float scale = 1.f;
            if constexpr (QSCALE) scale = ((col % 192) < 64) ? 0.125f : 1.f;
#pragma unroll
            for (int r = 0; r < 4; ++r) {
                float vv = acc[rt][ct][r] * scale;
                if constexpr (OUT_BF16)
                    ((unsigned short*)Cv)[(size_t)(row + r) * N + col] = f2bf(vv);
                else
                    ((float*)Cv)[(size_t)(row + r) * N + col] = vv;
            }
        }
}

// ---------------------------------------------------------------------------
// 64x64 bf16 MFMA GEMM (known-good; output projection — grid 1024)
// ---------------------------------------------------------------------------
template <bool OUT_BF16, bool QSCALE>
__global__ __launch_bounds__(256)
void gemm_bt_mfma(const unsigned short* __restrict__ A,
                  const unsigned short* __restrict__ Bw,
                  void* __restrict__ Cv, int M, int N, int K) {
    __shared__ unsigned short As[64 * 64];
    __shared__ unsigned short Bs[64 * 64];
    char* const AsB = (char*)As;
    char* const BsB = (char*)Bs;
    const int tid  = threadIdx.x;
    const int lane = tid & 63;
    const int w    = tid >> 6;
    const int lg   = lane >> 4;
    const int lq   = lane & 15;
    const int bm = blockIdx.y * 64;
    const int bn = blockIdx.x * 64;
    const int wr = (w >> 1) * 32;
    const int wc = (w & 1) * 32;
    const int sr = tid >> 2;
    const int sc = (tid & 3) * 16;
    const int swzS = (sr & 7) << 4;

    f32x4 acc[2][2];
#pragma unroll
    for (int i = 0; i < 2; ++i)
#pragma unroll
        for (int j = 0; j < 2; ++j) acc[i][j] = (f32x4){0.f, 0.f, 0.f, 0.f};

    const unsigned short* ap = A  + (size_t)(bm + sr) * K + sc;
    const unsigned short* bp = Bw + (size_t)(bn + sr) * K + sc;

    for (int k0 = 0; k0 < K; k0 += 64) {
        __syncthreads();
        u16x8 av0 = *(const u16x8*)(ap + k0);
        u16x8 av1 = *(const u16x8*)(ap + k0 + 8);
        u16x8 bv0 = *(const u16x8*)(bp + k0);
        u16x8 bv1 = *(const u16x8*)(bp + k0 + 8);
        *(u16x8*)(AsB + sr * 128 + ((sc * 2)      ^ swzS)) = av0;
        *(u16x8*)(AsB + sr * 128 + ((sc * 2 + 16) ^ swzS)) = av1;
        *(u16x8*)(BsB + sr * 128 + ((sc * 2)      ^ swzS)) = bv0;
        *(u16x8*)(BsB + sr * 128 + ((sc * 2 + 16) ^ swzS)) = bv1;
        __syncthreads();

        bf16x8 af[2][2], bfr[2][2];
#pragma unroll
        for (int rt = 0; rt < 2; ++rt) {
            const int row = wr + rt * 16 + lq;
            const int sz = (row & 7) << 4;
            af[rt][0] = *(const bf16x8*)(AsB + row * 128 + ((lg * 16)      ^ sz));
            af[rt][1] = *(const bf16x8*)(AsB + row * 128 + ((64 + lg * 16) ^ sz));
        }
#pragma unroll
        for (int ct = 0; ct < 2; ++ct) {
            const int row = wc + ct * 16 + lq;
            const int sz = (row & 7) << 4;
            bfr[ct][0] = *(const bf16x8*)(BsB + row * 128 + ((lg * 16)      ^ sz));
            bfr[ct][1] = *(const bf16x8*)(BsB + row * 128 + ((64 + lg * 16) ^ sz));
        }
#pragma unroll
        for (int rt = 0; rt < 2; ++rt)
#pragma unroll
            for (int ct = 0; ct < 2; ++ct) {
                acc[rt][ct] = __builtin_amdgcn_mfma_f32_16x16x32_bf16(af[rt][0], bfr[ct][0], acc[rt][ct], 0, 0, 0);
                acc[rt][ct] = __builtin_amdgcn_mfma_f32_16x16x32_bf16(af[rt][1], bfr[ct][1], acc[rt][ct], 0, 0, 0);
            }
    }

#pragma unroll
    for (int rt = 0; rt < 2; ++rt)
#pragma unroll
        for (int ct = 0; ct < 2; ++ct) {
            const int row = bm + wr + rt * 16 + lg * 4;
            const int col = bn + wc + ct * 16 + lq;
            float scale = 1.f;
            if constexpr (QSCALE) scale = ((col % 192) < 64) ? 0.125f : 1.f;
#pragma unroll
            for (int r = 0; r < 4; ++r) {
                float vv = acc[rt][ct][r] * scale;
                if constexpr (OUT_BF16)
                    ((unsigned short*)Cv)[(size_t)(row + r) * N + col] = f2bf(vv);
                else
                    ((float*)Cv)[(size_t)(row + r) * N + col] = vv;
            }
        }
}

// ---------------------------------------------------------------------------
// Flash attention partial, swapped-QK^T 32x32x16 (round-3 body, proven).
// Grid (S/128 * 2, H, B), block 256 = 4 waves, 32 q-rows/wave.
// blockIdx.x = qb*2 + part: this block handles keys [part*1024, +1024).
// Writes normalized bf16 partial O [part][b][h][q][d] + LSE z (fp32).
// ---------------------------------------------------------------------------
__global__ __launch_bounds__(256)
void attn_part(const unsigned short* __restrict__ qkv, const int* __restrict__ mask,
               unsigned short* __restrict__ Po, float* __restrict__ Zp) {
    __shared__ unsigned short Ks[64 * 64];
    __shared__ unsigned short Vt[64 * 64];
    __shared__ __align__(16) float MskF[64];
    char* const KsB = (char*)Ks;
    char* const VtB = (char*)Vt;

    const int tid  = threadIdx.x;
    const int lane = tid & 63;
    const int w    = tid >> 6;
    const int ln   = lane & 31;
    const int hi   = lane >> 5;
    const int part = blockIdx.x & 1;
    const int q0   = (blockIdx.x >> 1) * 128;
    const int h  = blockIdx.y;
    const int b  = blockIdx.z;
    const size_t baseBH = (size_t)b * S_LEN * QKV_LD + (size_t)h * (3 * D_DIM);
    const unsigned short* const kv = qkv + baseBH;

    // Q as B-frags (pre-scaled by 0.125): qf[kk] = Q[q=ln][d=kk*16+hi*8+j]
    bf16x8 qf[4];
    {
        const unsigned short* qp = kv + (size_t)(q0 + w * 32 + ln) * QKV_LD + hi * 8;
#pragma unroll
        for (int kk = 0; kk < 4; ++kk)
            qf[kk] = *(const bf16x8*)(qp + kk * 16);
    }

    f32x16 accO[2];
#pragma unroll
    for (int dt = 0; dt < 2; ++dt)
#pragma unroll
        for (int r = 0; r < 16; ++r) accO[dt][r] = 0.f;
    float mrun = 0.f, lrow = 0.f;   // bias -3e4 -> masked p == 0 under m>=0

    const int ksr = tid >> 2;          // K staging row (key)
    const int ksc = (tid & 3) * 16;    // K staging d-offset
    const int vkb = (tid & 15) * 4;    // V staging key base
    const int vdb = (tid >> 4) * 4;    // V staging d base

    const int kvbase = part * 1024;
    for (int it = 0; it < 16; ++it) {
        const int kv0 = kvbase + it * 64;
        __syncthreads();
        {   // stage K [key][d], swizzled
            const unsigned short* kp = kv + (size_t)(kv0 + ksr) * QKV_LD + D_DIM + ksc;
            u16x8 a0 = *(const u16x8*)kp;
            u16x8 a1 = *(const u16x8*)(kp + 8);
            const int swz = (ksr & 7) << 4;
            *(u16x8*)(KsB + ksr * 128 + ((ksc * 2)      ^ swz)) = a0;
            *(u16x8*)(KsB + ksr * 128 + ((ksc * 2 + 16) ^ swz)) = a1;
        }
        {   // stage V transposed [d][key], swizzled
            u16x4 vr[4];
#pragma unroll
            for (int i = 0; i < 4; ++i)
                vr[i] = *(const u16x4*)(kv + (size_t)(kv0 + vkb + i) * QKV_LD + 2 * D_DIM + vdb);
#pragma unroll
            for (int j = 0; j < 4; ++j) {
                u16x4 o = { vr[0][j], vr[1][j], vr[2][j], vr[3][j] };
                const int row = vdb + j;
                *(u16x4*)(VtB + row * 128 + ((vkb * 2) ^ ((row & 7) << 4))) = o;
            }
        }
        if (tid < 64) MskF[tid] = (mask[b * S_LEN + kv0 + tid] != 0) ? 0.f : -30000.f;
        __syncthreads();

        // ---- S^T = K Q^T + bias. key = (r&3)+8*(r>>2)+4*hi+32*ks, q = ln ----
        f32x16 s[2];
#pragma unroll
        for (int ks = 0; ks < 2; ++ks)
#pragma unroll
            for (int m = 0; m < 4; ++m) {
                f32x4 b4 = *(const f32x4*)(&MskF[ks * 32 + m * 8 + hi * 4]);
#pragma unroll
                for (int i = 0; i < 4; ++i) s[ks][m * 4 + i] = b4[i];
            }
#pragma unroll
        for (int ks = 0; ks < 2; ++ks) {
            const int krow = ks * 32 + ln;
            const int swz = (ln & 7) << 4;
#pragma unroll
            for (int kk = 0; kk < 4; ++kk) {
                bf16x8 kf = *(const bf16x8*)(KsB + krow * 128 + (((kk * 16 + hi * 8) * 2) ^ swz));
                s[ks] = __builtin_amdgcn_mfma_f32_32x32x16_bf16(kf, qf[kk], s[ks], 0, 0, 0);
            }
        }

        // ---- online softmax with defer-max ----
        float tm = -3.4e38f;
#pragma unroll
        for (int ks = 0; ks < 2; ++ks)
#pragma unroll
            for (int r = 0; r < 16; ++r) tm = fmaxf(tm, s[ks][r]);
        {
            i32x2 rr = __builtin_amdgcn_permlane32_swap(__float_as_int(tm), __float_as_int(tm), false, false);
            tm = fmaxf(__int_as_float(rr[0]), __int_as_float(rr[1]));
        }
        float rsum = 0.f;
        if (__all(tm <= mrun + 8.f)) {          // defer: keep old max, skip rescale
#pragma unroll
            for (int ks = 0; ks < 2; ++ks)
#pragma unroll
                for (int r = 0; r < 16; ++r) {
                    float p = __expf(s[ks][r] - mrun);
                    s[ks][r] = p;
                    rsum += p;
                }
            i32x2 rr = __builtin_amdgcn_permlane32_swap(__float_as_int(rsum), __float_as_int(rsum), false, false);
            lrow += __int_as_float(rr[0]) + __int_as_float(rr[1]);
        } else {
            const float mnew = fmaxf(mrun, tm);
            const float fsc = __expf(mrun - mnew);
#pragma unroll
            for (int ks = 0; ks < 2; ++ks)
#pragma unroll
                for (int r = 0; r < 16; ++r) {
                    float p = __expf(s[ks][r] - mnew);
                    s[ks][r] = p;
                    rsum += p;
                }
            i32x2 rr = __builtin_amdgcn_permlane32_swap(__float_as_int(rsum), __float_as_int(rsum), false, false);
            lrow = lrow * fsc + __int_as_float(rr[0]) + __int_as_float(rr[1]);
            mrun = mnew;
#pragma unroll
            for (int dt = 0; dt < 2; ++dt)
#pragma unroll
                for (int r = 0; r < 16; ++r) accO[dt][r] *= fsc;
        }

        // ---- assemble P^T B-frags in-register ----
        bf16x8 pb[4];
#pragma unroll
        for (int ks = 0; ks < 2; ++ks) {
            unsigned wA[4], wB[4];
#pragma unroll
            for (int m = 0; m < 4; ++m) {
                wA[m] = cvtpk_bf16(s[ks][4 * m + 0], s[ks][4 * m + 1]);
                wB[m] = cvtpk_bf16(s[ks][4 * m + 2], s[ks][4 * m + 3]);
            }
#pragma unroll
            for (int t = 0; t < 2; ++t) {
                i32x2 ra = __builtin_amdgcn_permlane32_swap((int)wA[2 * t], (int)wA[2 * t + 1], false, false);
                i32x2 rb = __builtin_amdgcn_permlane32_swap((int)wB[2 * t], (int)wB[2 * t + 1], false, false);
                union { unsigned u[4]; bf16x8 v; } uu;
                uu.u[0] = (unsigned)ra[0];
                uu.u[1] = (unsigned)rb[0];
                uu.u[2] = (unsigned)ra[1];
                uu.u[3] = (unsigned)rb[1];
                pb[ks * 2 + t] = uu.v;
            }
        }

        // ---- O^T += V^T P^T ----
#pragma unroll
        for (int dt = 0; dt < 2; ++dt) {
            const int drow = dt * 32 + ln;
            const int swz = (ln & 7) << 4;
#pragma unroll
            for (int n = 0; n < 4; ++n) {
                bf16x8 va = *(const bf16x8*)(VtB + drow * 128 + (((n * 16 + hi * 8) * 2) ^ swz));
                accO[dt] = __builtin_amdgcn_mfma_f32_32x32x16_bf16(va, pb[n], accO[dt], 0, 0, 0);
            }
        }
    }

    // ---- partial epilogue: normalized bf16 O + LSE; d = i+8m+4hi+32dt ----
    const int q = q0 + w * 32 + ln;
    const float inv = 1.f / lrow;
    unsigned short* po = Po + (((size_t)(part * B_NUM + b) * H_NUM + h) * S_LEN + q) * D_DIM;
#pragma unroll
    for (int dt = 0; dt < 2; ++dt)
#pragma unroll
        for (int m = 0; m < 4; ++m) {
            u16x4 o;
#pragma unroll
            for (int i = 0; i < 4; ++i) o[i] = f2bf(accO[dt][4 * m + i] * inv);
            *(u16x4*)(po + dt * 32 + m * 8 + hi * 4) = o;
        }
    if (hi == 0)
        Zp[((size_t)(part * B_NUM + b) * H_NUM + h) * S_LEN + q] = mrun + __logf(lrow);
}

// ---------------------------------------------------------------------------
// Merge the two KV-half partials into vbuf (B,S,E) bf16, e = h*64+d.
// idx = (((b*S+q)*H + h)*8 + j); each thread combines 8 elements (16B).
// ---------------------------------------------------------------------------
__global__ __launch_bounds__(256)
void attn_merge(const unsigned short* __restrict__ Po, const float* __restrict__ Zp,
                unsigned short* __restrict__ vbuf) {
    const int idx = blockIdx.x * 256 + threadIdx.x;   // 0 .. B*S*H*8-1
    const int j   = idx & 7;
    const int rh  = idx >> 3;          // (b*S+q)*H + h
    const int h   = rh & (H_NUM - 1);
    const int bq  = rh >> 4;           // b*S + q
    const int b   = bq >> 11;
    const int q   = bq & (S_LEN - 1);

    const size_t prow0 = ((size_t)(b)          * H_NUM + h) * S_LEN + q;
    const size_t prow1 = ((size_t)(B_NUM + b)  * H_NUM + h) * S_LEN + q;
    const float z0 = Zp[prow0];
    const float z1 = Zp[prow1];
    const float zm = fmaxf(z0, z1);
    float w0 = __expf(z0 - zm);
    float w1 = __expf(z1 - zm);
    const float is = 1.f / (w0 + w1);
    w0 *= is; w1 *= is;

    u16x8 a = *(const u16x8*)(Po + prow0 * D_DIM + j * 8);
    u16x8 c = *(const u16x8*)(Po + prow1 * D_DIM + j * 8);
    u16x8 o;
#pragma unroll
    for (int k = 0; k < 8; ++k)
        o[k] = f2bf(bf2f(a[k]) * w0 + bf2f(c[k]) * w1);
    *(u16x8*)(vbuf + (size_t)bq * E_DIM + h * D_DIM + j * 8) = o;
}

// ---------------------------------------------------------------------------
extern "C" void kernel_launch(void* const* d_in, const int* in_sizes, int n_in,
                              void* d_out, int out_size, void* d_ws, size_t ws_size,
                              hipStream_t stream) {
    const float* x      = (const float*)d_in[0];
    const int*   mask   = (const int*)d_in[1];
    const float* w_qkv  = (const float*)d_in[2];
    const float* w_o    = (const float*)d_in[3];
    float*       out    = (float*)d_out;

    const int M = B_NUM * S_LEN;     // 4096
    unsigned short* qkvb = (unsigned short*)d_ws;                    // M x 3E      (25.2 MB)
    unsigned short* vbuf = qkvb + (size_t)M * 3 * E_DIM;             // M x E       ( 8.4 MB)
    unsigned short* xb   = vbuf + (size_t)M * E_DIM;                 // M x E       ( 8.4 MB)
    unsigned short* wqb  = xb   + (size_t)M * E_DIM;                 // 3E x E      ( 6.3 MB)
    unsigned short* wob  = wqb  + (size_t)3 * E_DIM * E_DIM;         // E x E       ( 2.1 MB)
    unsigned short* Po   = wob  + (size_t)E_DIM * E_DIM;             // 2*M*E bf16  (16.8 MB)
    float*          Zp   = (float*)(Po + (size_t)2 * M * E_DIM);     // 2*M*H f32   ( 0.5 MB)

    dim3 blk(256);
    {
        int n4;
        n4 = M * E_DIM / 4;
        cvt_f32_bf16<<<dim3((n4 + 255) / 256), blk, 0, stream>>>(x, xb, n4);
        n4 = 3 * E_DIM * E_DIM / 4;
        cvt_f32_bf16<<<dim3((n4 + 255) / 256), blk, 0, stream>>>(w_qkv, wqb, n4);
        n4 = E_DIM * E_DIM / 4;
        cvt_f32_bf16<<<dim3((n4 + 255) / 256), blk, 0, stream>>>(w_o, wob, n4);
    }

    // QKV projection (q columns pre-scaled by 0.125), bf16 out, 128^2 tile
    gemm_bt_mfma128<true, true><<<dim3(3 * E_DIM / 128, M / 128), blk, 0, stream>>>(
        xb, wqb, qkvb, M, 3 * E_DIM, E_DIM);

    // flash attention partials: 2 KV halves per q-block
    attn_part<<<dim3((S_LEN / 128) * 2, H_NUM, B_NUM), blk, 0, stream>>>(
        qkvb, mask, Po, Zp);

    // merge partials -> vbuf
    attn_merge<<<dim3(B_NUM * S_LEN * H_NUM * 8 / 256), blk, 0, stream>>>(Po, Zp, vbuf);

    // output projection, fp32 out, 64^2 tile (grid 1024)
    gemm_bt_mfma<false, false><<<dim3(E_DIM / 64, M / 64), blk, 0, stream>>>(
        vbuf, wob, out, M, E_DIM, E_DIM);
}

// Round 6
// 127.804 us; speedup vs baseline: 1.9760x; 1.1899x over previous
//
#include <hip/hip_runtime.h>
#include <hip/hip_bf16.h>

#define B_NUM 2
#define S_LEN 2048
#define E_DIM 1024
#define H_NUM 16
#define D_DIM 64
#define QKV_LD 3072
// 1/sqrt(64) * log2(e): folded so softmax exp is a bare v_exp_f32 (exp2)
#define QSCALE_LOG2E 0.18033688011112042f

typedef __attribute__((ext_vector_type(8))) short bf16x8;
typedef __attribute__((ext_vector_type(8))) unsigned short u16x8;
typedef __attribute__((ext_vector_type(4))) unsigned short u16x4;
typedef __attribute__((ext_vector_type(4))) float f32x4;
typedef __attribute__((ext_vector_type(16))) float f32x16;
typedef __attribute__((ext_vector_type(2))) int i32x2;

static __device__ __forceinline__ unsigned short f2bf(float f) {
    union { float f; unsigned int u; } v; v.f = f;
    unsigned int r = v.u + 0x7fffu + ((v.u >> 16) & 1u);   // RNE
    return (unsigned short)(r >> 16);
}

static __device__ __forceinline__ unsigned cvtpk_bf16(float lo, float hi) {
    unsigned r;
    asm("v_cvt_pk_bf16_f32 %0, %1, %2" : "=v"(r) : "v"(lo), "v"(hi));
    return r;
}

// async global->LDS, 16B per lane; LDS dest = uniform base + lane*16
static __device__ __forceinline__ void gload16(const void* gsrc, void* ldst) {
    __builtin_amdgcn_global_load_lds(
        (const __attribute__((address_space(1))) unsigned int*)gsrc,
        (__attribute__((address_space(3))) unsigned int*)ldst, 16, 0, 0);
}

// ---------------------------------------------------------------------------
// fp32 -> bf16 bulk convert
// ---------------------------------------------------------------------------
__global__ __launch_bounds__(256)
void cvt_f32_bf16(const float* __restrict__ in, unsigned short* __restrict__ outp, int n4) {
    int i = blockIdx.x * blockDim.x + threadIdx.x;
    if (i < n4) {
        float4 f = ((const float4*)in)[i];
        u16x4 o = { f2bf(f.x), f2bf(f.y), f2bf(f.z), f2bf(f.w) };
        ((u16x4*)outp)[i] = o;
    }
}

// ---------------------------------------------------------------------------
// 128x128 bf16 MFMA GEMM, BK=64, 4 waves. global_load_lds staging with
// pre-swizzled global source. (proven rounds 4-5)
// ---------------------------------------------------------------------------
template <bool OUT_BF16, bool QSCALE>
__global__ __launch_bounds__(256)
void gemm_bt_mfma128(const unsigned short* __restrict__ A,
                     const unsigned short* __restrict__ Bw,
                     void* __restrict__ Cv, int M, int N, int K) {
    __shared__ unsigned short As[128 * 64];
    __shared__ unsigned short Bs[128 * 64];
    char* const AsB = (char*)As;
    char* const BsB = (char*)Bs;
    const int tid  = threadIdx.x;
    const int lane = tid & 63;
    const int w    = tid >> 6;
    const int lg   = lane >> 4;
    const int lq   = lane & 15;
    const int bm = blockIdx.y * 128;
    const int bn = blockIdx.x * 128;
    const int wr = (w >> 1) * 64;
    const int wc = (w & 1) * 64;
    const int lrow8 = lane >> 3;
    const int gblk  = (lane & 7) ^ lrow8;

    f32x4 acc[4][4];
#pragma unroll
    for (int i = 0; i < 4; ++i)
#pragma unroll
        for (int j = 0; j < 4; ++j) acc[i][j] = (f32x4){0.f, 0.f, 0.f, 0.f};

    for (int k0 = 0; k0 < K; k0 += 64) {
        __syncthreads();
#pragma unroll
        for (int t = 0; t < 4; ++t) {
            const int c = w * 4 + t;
            const int row = c * 8 + lrow8;
            gload16(A + (size_t)(bm + row) * K + k0 + gblk * 8, AsB + c * 1024);
            gload16(Bw + (size_t)(bn + row) * K + k0 + gblk * 8, BsB + c * 1024);
        }
        __syncthreads();

        bf16x8 af[4][2], bfr[4][2];
#pragma unroll
        for (int rt = 0; rt < 4; ++rt) {
            const int row = wr + rt * 16 + lq;
            const int sz = (row & 7) << 4;
            af[rt][0] = *(const bf16x8*)(AsB + row * 128 + ((lg * 16)      ^ sz));
            af[rt][1] = *(const bf16x8*)(AsB + row * 128 + ((64 + lg * 16) ^ sz));
        }
#pragma unroll
        for (int ct = 0; ct < 4; ++ct) {
            const int row = wc + ct * 16 + lq;
            const int sz = (row & 7) << 4;
            bfr[ct][0] = *(const bf16x8*)(BsB + row * 128 + ((lg * 16)      ^ sz));
            bfr[ct][1] = *(const bf16x8*)(BsB + row * 128 + ((64 + lg * 16) ^ sz));
        }
#pragma unroll
        for (int rt = 0; rt < 4; ++rt)
#pragma unroll
            for (int ct = 0; ct < 4; ++ct) {
                acc[rt][ct] = __builtin_amdgcn_mfma_f32_16x16x32_bf16(af[rt][0], bfr[ct][0], acc[rt][ct], 0, 0, 0);
                acc[rt][ct] = __builtin_amdgcn_mfma_f32_16x16x32_bf16(af[rt][1], bfr[ct][1], acc[rt][ct], 0, 0, 0);
            }
    }

#pragma unroll
    for (int rt = 0; rt < 4; ++rt)
#pragma unroll
        for (int ct = 0; ct < 4; ++ct) {
            const int row = bm + wr + rt * 16 + lg * 4;
            const int col = bn + wc + ct * 16 + lq;
            float scale = 1.f;
            if constexpr (QSCALE) scale = ((col % 192) < 64) ? QSCALE_LOG2E : 1.f;
#pragma unroll
            for (int r = 0; r < 4; ++r) {
                float vv = acc[rt][ct][r] * scale;
                if constexpr (OUT_BF16)
                    ((unsigned short*)Cv)[(size_t)(row + r) * N + col] = f2bf(vv);
                else
                    ((float*)Cv)[(size_t)(row + r) * N + col] = vv;
            }
        }
}

// ---------------------------------------------------------------------------
// 64x64 bf16 MFMA GEMM (known-good; output projection)
// ---------------------------------------------------------------------------
template <bool OUT_BF16, bool QSCALE>
__global__ __launch_bounds__(256)
void gemm_bt_mfma(const unsigned short* __restrict__ A,
                  const unsigned short* __restrict__ Bw,
                  void* __restrict__ Cv, int M, int N, int K) {
    __shared__ unsigned short As[64 * 64];
    __shared__ unsigned short Bs[64 * 64];
    char* const AsB = (char*)As;
    char* const BsB = (char*)Bs;
    const int tid  = threadIdx.x;
    const int lane = tid & 63;
    const int w    = tid >> 6;
    const int lg   = lane >> 4;
    const int lq   = lane & 15;
    const int bm = blockIdx.y * 64;
    const int bn = blockIdx.x * 64;
    const int wr = (w >> 1) * 32;
    const int wc = (w & 1) * 32;
    const int sr = tid >> 2;
    const int sc = (tid & 3) * 16;
    const int swzS = (sr & 7) << 4;

    f32x4 acc[2][2];
#pragma unroll
    for (int i = 0; i < 2; ++i)
#pragma unroll
        for (int j = 0; j < 2; ++j) acc[i][j] = (f32x4){0.f, 0.f, 0.f, 0.f};

    const unsigned short* ap = A  + (size_t)(bm + sr) * K + sc;
    const unsigned short* bp = Bw + (size_t)(bn + sr) * K + sc;

    for (int k0 = 0; k0 < K; k0 += 64) {
        __syncthreads();
        u16x8 av0 = *(const u16x8*)(ap + k0);
        u16x8 av1 = *(const u16x8*)(ap + k0 + 8);
        u16x8 bv0 = *(const u16x8*)(bp + k0);
        u16x8 bv1 = *(const u16x8*)(bp + k0 + 8);
        *(u16x8*)(AsB + sr * 128 + ((sc * 2)      ^ swzS)) = av0;
        *(u16x8*)(AsB + sr * 128 + ((sc * 2 + 16) ^ swzS)) = av1;
        *(u16x8*)(BsB + sr * 128 + ((sc * 2)      ^ swzS)) = bv0;
        *(u16x8*)(BsB + sr * 128 + ((sc * 2 + 16) ^ swzS)) = bv1;
        __syncthreads();

        bf16x8 af[2][2], bfr[2][2];
#pragma unroll
        for (int rt = 0; rt < 2; ++rt) {
            const int row = wr + rt * 16 + lq;
            const int sz = (row & 7) << 4;
            af[rt][0] = *(const bf16x8*)(AsB + row * 128 + ((lg * 16)      ^ sz));
            af[rt][1] = *(const bf16x8*)(AsB + row * 128 + ((64 + lg * 16) ^ sz));
        }
#pragma unroll
        for (int ct = 0; ct < 2; ++ct) {
            const int row = wc + ct * 16 + lq;
            const int sz = (row & 7) << 4;
            bfr[ct][0] = *(const bf16x8*)(BsB + row * 128 + ((lg * 16)      ^ sz));
            bfr[ct][1] = *(const bf16x8*)(BsB + row * 128 + ((64 + lg * 16) ^ sz));
        }
#pragma unroll
        for (int rt = 0; rt < 2; ++rt)
#pragma unroll
            for (int ct = 0; ct < 2; ++ct) {
                acc[rt][ct] = __builtin_amdgcn_mfma_f32_16x16x32_bf16(af[rt][0], bfr[ct][0], acc[rt][ct], 0, 0, 0);
                acc[rt][ct] = __builtin_amdgcn_mfma_f32_16x16x32_bf16(af[rt][1], bfr[ct][1], acc[rt][ct], 0, 0, 0);
            }
    }

#pragma unroll
    for (int rt = 0; rt < 2; ++rt)
#pragma unroll
        for (int ct = 0; ct < 2; ++ct) {
            const int row = bm + wr + rt * 16 + lg * 4;
            const int col = bn + wc + ct * 16 + lq;
            float scale = 1.f;
            if constexpr (QSCALE) scale = ((col % 192) < 64) ? QSCALE_LOG2E : 1.f;
#pragma unroll
            for (int r = 0; r < 4; ++r) {
                float vv = acc[rt][ct][r] * scale;
                if constexpr (OUT_BF16)
                    ((unsigned short*)Cv)[(size_t)(row + r) * N + col] = f2bf(vv);
                else
                    ((float*)Cv)[(size_t)(row + r) * N + col] = vv;
            }
        }
}

// ---------------------------------------------------------------------------
// Flash attention v6: swapped-QK^T 32x32x16, single-pass, NO-MAX softmax
// (p = exp2(bias + q.k*0.125*log2e); masked bias -30000 -> p==0), LDS
// double-buffered K/V with one barrier per tile, prefetch issued at loop
// top (K via global_load_lds, V via reg staging), bias row staged once.
// Grid (S/128, H, B), block 256 = 4 waves, 32 q-rows/wave.
// ---------------------------------------------------------------------------
__global__ __launch_bounds__(256)
void attn_v6(const unsigned short* __restrict__ qkv, const int* __restrict__ mask,
             unsigned short* __restrict__ vout) {
    __shared__ __align__(16) char KsP[2][8192];
    __shared__ __align__(16) char VtP[2][8192];
    __shared__ __align__(16) float BiasF[S_LEN];

    const int tid  = threadIdx.x;
    const int lane = tid & 63;
    const int w    = tid >> 6;
    const int ln   = lane & 31;
    const int hi   = lane >> 5;
    const int q0 = blockIdx.x * 128;
    const int h  = blockIdx.y;
    const int b  = blockIdx.z;
    const size_t baseBH = (size_t)b * S_LEN * QKV_LD + (size_t)h * (3 * D_DIM);
    const unsigned short* const kv = qkv + baseBH;

    // ---- stage full bias row once: 2048 floats, 256 threads x 8 ----
    {
        const int4* mr = (const int4*)(mask + (size_t)b * S_LEN);
        int4 m0 = mr[tid * 2];
        int4 m1 = mr[tid * 2 + 1];
        float4 f0 = { m0.x ? 0.f : -30000.f, m0.y ? 0.f : -30000.f,
                      m0.z ? 0.f : -30000.f, m0.w ? 0.f : -30000.f };
        float4 f1 = { m1.x ? 0.f : -30000.f, m1.y ? 0.f : -30000.f,
                      m1.z ? 0.f : -30000.f, m1.w ? 0.f : -30000.f };
        ((float4*)BiasF)[tid * 2]     = f0;
        ((float4*)BiasF)[tid * 2 + 1] = f1;
    }

    // Q as B-frags (pre-scaled by 0.125*log2e): qf[kk] = Q[q=ln][d=kk*16+hi*8+j]
    bf16x8 qf[4];
    {
        const unsigned short* qp = kv + (size_t)(q0 + w * 32 + ln) * QKV_LD + hi * 8;
#pragma unroll
        for (int kk = 0; kk < 4; ++kk)
            qf[kk] = *(const bf16x8*)(qp + kk * 16);
    }

    const int lrow8 = lane >> 3;
    const int gblk  = (lane & 7) ^ lrow8;   // pre-swizzled 16B block for K stage
    const int vkb = (tid & 15) * 4;         // V staging key base
    const int vdb = (tid >> 4) * 4;         // V staging d base

    // ---- stage tile 0 into buffer 0 ----
    {
#pragma unroll
        for (int t = 0; t < 2; ++t) {
            const int c = w * 2 + t;
            gload16(kv + (size_t)(c * 8 + lrow8) * QKV_LD + D_DIM + gblk * 8,
                    KsP[0] + c * 1024);
        }
        u16x4 vr[4];
#pragma unroll
        for (int i = 0; i < 4; ++i)
            vr[i] = *(const u16x4*)(kv + (size_t)(vkb + i) * QKV_LD + 2 * D_DIM + vdb);
#pragma unroll
        for (int j = 0; j < 4; ++j) {
            u16x4 o = { vr[0][j], vr[1][j], vr[2][j], vr[3][j] };
            const int row = vdb + j;
            *(u16x4*)(VtP[0] + row * 128 + ((vkb * 2) ^ ((row & 7) << 4))) = o;
        }
    }
    __syncthreads();

    f32x16 accO[2];
#pragma unroll
    for (int dt = 0; dt < 2; ++dt)
#pragma unroll
        for (int r = 0; r < 16; ++r) accO[dt][r] = 0.f;
    f32x4 rsumv = (f32x4){0.f, 0.f, 0.f, 0.f};

    for (int it = 0; it < S_LEN / 64; ++it) {
        const int cur = it & 1;
        const int kv0 = it * 64;
        char* const KsC = KsP[cur];
        char* const VtC = VtP[cur];
        const bool pf = (it < S_LEN / 64 - 1);

        // ---- prefetch tile it+1 into buffer cur^1 (issue only) ----
        u16x4 vr[4];
        if (pf) {
            const int kvn = kv0 + 64;
#pragma unroll
            for (int t = 0; t < 2; ++t) {
                const int c = w * 2 + t;
                gload16(kv + (size_t)(kvn + c * 8 + lrow8) * QKV_LD + D_DIM + gblk * 8,
                        KsP[cur ^ 1] + c * 1024);
            }
#pragma unroll
            for (int i = 0; i < 4; ++i)
                vr[i] = *(const u16x4*)(kv + (size_t)(kvn + vkb + i) * QKV_LD + 2 * D_DIM + vdb);
        }

        // ---- S^T = K Q^T + bias (log2 domain) ----
        f32x16 s[2];
#pragma unroll
        for (int ks = 0; ks < 2; ++ks)
#pragma unroll
            for (int m = 0; m < 4; ++m) {
                f32x4 b4 = *(const f32x4*)(&BiasF[kv0 + ks * 32 + m * 8 + hi * 4]);
#pragma unroll
                for (int i = 0; i < 4; ++i) s[ks][m * 4 + i] = b4[i];
            }
        __builtin_amdgcn_s_setprio(1);
#pragma unroll
        for (int ks = 0; ks < 2; ++ks) {
            const int krow = ks * 32 + ln;
            const int swz = (ln & 7) << 4;
#pragma unroll
            for (int kk = 0; kk < 4; ++kk) {
                bf16x8 kf = *(const bf16x8*)(KsC + krow * 128 + (((kk * 16 + hi * 8) * 2) ^ swz));
                s[ks] = __builtin_amdgcn_mfma_f32_32x32x16_bf16(kf, qf[kk], s[ks], 0, 0, 0);
            }
        }
        __builtin_amdgcn_s_setprio(0);

        // ---- p = exp2(s); 4 independent row-sum accumulators ----
#pragma unroll
        for (int ks = 0; ks < 2; ++ks)
#pragma unroll
            for (int r = 0; r < 16; ++r) {
                float p = __builtin_amdgcn_exp2f(s[ks][r]);
                s[ks][r] = p;
                rsumv[r & 3] += p;
            }

        // ---- assemble P^T B-frags in-register ----
        bf16x8 pb[4];
#pragma unroll
        for (int ks = 0; ks < 2; ++ks) {
            unsigned wA[4], wB[4];
#pragma unroll
            for (int m = 0; m < 4; ++m) {
                wA[m] = cvtpk_bf16(s[ks][4 * m + 0], s[ks][4 * m + 1]);
                wB[m] = cvtpk_bf16(s[ks][4 * m + 2], s[ks][4 * m + 3]);
            }
#pragma unroll
            for (int t = 0; t < 2; ++t) {
                i32x2 ra = __builtin_amdgcn_permlane32_swap((int)wA[2 * t], (int)wA[2 * t + 1], false, false);
                i32x2 rb = __builtin_amdgcn_permlane32_swap((int)wB[2 * t], (int)wB[2 * t + 1], false, false);
                union { unsigned u[4]; bf16x8 v; } uu;
                uu.u[0] = (unsigned)ra[0];
                uu.u[1] = (unsigned)rb[0];
                uu.u[2] = (unsigned)ra[1];
                uu.u[3] = (unsigned)rb[1];
                pb[ks * 2 + t] = uu.v;
            }
        }

        // ---- O^T += V^T P^T ----
        __builtin_amdgcn_s_setprio(1);
#pragma unroll
        for (int dt = 0; dt < 2; ++dt) {
            const int drow = dt * 32 + ln;
            const int swz = (ln & 7) << 4;
#pragma unroll
            for (int n = 0; n < 4; ++n) {
                bf16x8 va = *(const bf16x8*)(VtC + drow * 128 + (((n * 16 + hi * 8) * 2) ^ swz));
                accO[dt] = __builtin_amdgcn_mfma_f32_32x32x16_bf16(va, pb[n], accO[dt], 0, 0, 0);
            }
        }
        __builtin_amdgcn_s_setprio(0);

        // ---- complete prefetch: V regs -> LDS (transposed, swizzled) ----
        if (pf) {
#pragma unroll
            for (int j = 0; j < 4; ++j) {
                u16x4 o = { vr[0][j], vr[1][j], vr[2][j], vr[3][j] };
                const int row = vdb + j;
                *(u16x4*)(VtP[cur ^ 1] + row * 128 + ((vkb * 2) ^ ((row & 7) << 4))) = o;
            }
        }
        __syncthreads();   // drains gload_lds (vmcnt) + ds_writes; flips buffers
    }

    // ---- epilogue: one partner-reduce of the row sum, normalize, store ----
    float rsum = rsumv[0] + rsumv[1] + rsumv[2] + rsumv[3];
    {
        i32x2 rr = __builtin_amdgcn_permlane32_swap(__float_as_int(rsum), __float_as_int(rsum), false, false);
        rsum = __int_as_float(rr[0]) + __int_as_float(rr[1]);
    }
    const float inv = 1.f / rsum;
    unsigned short* op = vout + (size_t)(b * S_LEN + q0 + w * 32 + ln) * E_DIM + h * D_DIM;
#pragma unroll
    for (int dt = 0; dt < 2; ++dt)
#pragma unroll
        for (int m = 0; m < 4; ++m) {
            u16x4 o;
#pragma unroll
            for (int i = 0; i < 4; ++i) o[i] = f2bf(accO[dt][4 * m + i] * inv);
            *(u16x4*)(op + dt * 32 + m * 8 + hi * 4) = o;
        }
}

// ---------------------------------------------------------------------------
extern "C" void kernel_launch(void* const* d_in, const int* in_sizes, int n_in,
                              void* d_out, int out_size, void* d_ws, size_t ws_size,
                              hipStream_t stream) {
    const float* x      = (const float*)d_in[0];
    const int*   mask   = (const int*)d_in[1];
    const float* w_qkv  = (const float*)d_in[2];
    const float* w_o    = (const float*)d_in[3];
    float*       out    = (float*)d_out;

    const int M = B_NUM * S_LEN;     // 4096
    unsigned short* qkvb = (unsigned short*)d_ws;                    // M x 3E
    unsigned short* vbuf = qkvb + (size_t)M * 3 * E_DIM;             // M x E
    unsigned short* xb   = vbuf + (size_t)M * E_DIM;                 // M x E
    unsigned short* wqb  = xb   + (size_t)M * E_DIM;                 // 3E x E
    unsigned short* wob  = wqb  + (size_t)3 * E_DIM * E_DIM;         // E x E

    dim3 blk(256);
    {
        int n4;
        n4 = M * E_DIM / 4;
        cvt_f32_bf16<<<dim3((n4 + 255) / 256), blk, 0, stream>>>(x, xb, n4);
        n4 = 3 * E_DIM * E_DIM / 4;
        cvt_f32_bf16<<<dim3((n4 + 255) / 256), blk, 0, stream>>>(w_qkv, wqb, n4);
        n4 = E_DIM * E_DIM / 4;
        cvt_f32_bf16<<<dim3((n4 + 255) / 256), blk, 0, stream>>>(w_o, wob, n4);
    }

    // QKV projection (q columns pre-scaled by 0.125*log2e), bf16 out
    gemm_bt_mfma128<true, true><<<dim3(3 * E_DIM / 128, M / 128), blk, 0, stream>>>(
        xb, wqb, qkvb, M, 3 * E_DIM, E_DIM);

    // flash attention v6 (single-pass, no-max softmax, double-buffered)
    attn_v6<<<dim3(S_LEN / 128, H_NUM, B_NUM), blk, 0, stream>>>(qkvb, mask, vbuf);

    // output projection, fp32 out
    gemm_bt_mfma<false, false><<<dim3(E_DIM / 64, M / 64), blk, 0, stream>>>(
        vbuf, wob, out, M, E_DIM, E_DIM);
}

// Round 7
// 125.745 us; speedup vs baseline: 2.0084x; 1.0164x over previous
//
#include <hip/hip_runtime.h>
#include <hip/hip_bf16.h>

#define B_NUM 2
#define S_LEN 2048
#define E_DIM 1024
#define H_NUM 16
#define D_DIM 64
#define QKV_LD 3072
// 1/sqrt(64) * log2(e): folded so softmax exp is a bare v_exp_f32 (exp2)
#define QSCALE_LOG2E 0.18033688011112042f

typedef __attribute__((ext_vector_type(8))) short bf16x8;
typedef __attribute__((ext_vector_type(8))) unsigned short u16x8;
typedef __attribute__((ext_vector_type(4))) unsigned short u16x4;
typedef __attribute__((ext_vector_type(4))) float f32x4;
typedef __attribute__((ext_vector_type(16))) float f32x16;
typedef __attribute__((ext_vector_type(2))) int i32x2;

static __device__ __forceinline__ unsigned short f2bf(float f) {
    union { float f; unsigned int u; } v; v.f = f;
    unsigned int r = v.u + 0x7fffu + ((v.u >> 16) & 1u);   // RNE
    return (unsigned short)(r >> 16);
}

static __device__ __forceinline__ unsigned cvtpk_bf16(float lo, float hi) {
    unsigned r;
    asm("v_cvt_pk_bf16_f32 %0, %1, %2" : "=v"(r) : "v"(lo), "v"(hi));
    return r;
}

// async global->LDS, 16B per lane; LDS dest = uniform base + lane*16
static __device__ __forceinline__ void gload16(const void* gsrc, void* ldst) {
    __builtin_amdgcn_global_load_lds(
        (const __attribute__((address_space(1))) unsigned int*)gsrc,
        (__attribute__((address_space(3))) unsigned int*)ldst, 16, 0, 0);
}

// ---------------------------------------------------------------------------
// fp32 -> bf16 bulk convert
// ---------------------------------------------------------------------------
__global__ __launch_bounds__(256)
void cvt_f32_bf16(const float* __restrict__ in, unsigned short* __restrict__ outp, int n4) {
    int i = blockIdx.x * blockDim.x + threadIdx.x;
    if (i < n4) {
        float4 f = ((const float4*)in)[i];
        u16x4 o = { f2bf(f.x), f2bf(f.y), f2bf(f.z), f2bf(f.w) };
        ((u16x4*)outp)[i] = o;
    }
}

// ---------------------------------------------------------------------------
// 128x128 bf16 MFMA GEMM, BK=64, 4 waves. global_load_lds staging with
// pre-swizzled global source. (proven rounds 4-6)
// ---------------------------------------------------------------------------
template <bool OUT_BF16, bool QSCALE>
__global__ __launch_bounds__(256)
void gemm_bt_mfma128(const unsigned short* __restrict__ A,
                     const unsigned short* __restrict__ Bw,
                     void* __restrict__ Cv, int M, int N, int K) {
    __shared__ unsigned short As[128 * 64];
    __shared__ unsigned short Bs[128 * 64];
    char* const AsB = (char*)As;
    char* const BsB = (char*)Bs;
    const int tid  = threadIdx.x;
    const int lane = tid & 63;
    const int w    = tid >> 6;
    const int lg   = lane >> 4;
    const int lq   = lane & 15;
    const int bm = blockIdx.y * 128;
    const int bn = blockIdx.x * 128;
    const int wr = (w >> 1) * 64;
    const int wc = (w & 1) * 64;
    const int lrow8 = lane >> 3;
    const int gblk  = (lane & 7) ^ lrow8;

    f32x4 acc[4][4];
#pragma unroll
    for (int i = 0; i < 4; ++i)
#pragma unroll
        for (int j = 0; j < 4; ++j) acc[i][j] = (f32x4){0.f, 0.f, 0.f, 0.f};

    for (int k0 = 0; k0 < K; k0 += 64) {
        __syncthreads();
#pragma unroll
        for (int t = 0; t < 4; ++t) {
            const int c = w * 4 + t;
            const int row = c * 8 + lrow8;
            gload16(A + (size_t)(bm + row) * K + k0 + gblk * 8, AsB + c * 1024);
            gload16(Bw + (size_t)(bn + row) * K + k0 + gblk * 8, BsB + c * 1024);
        }
        __syncthreads();

        bf16x8 af[4][2], bfr[4][2];
#pragma unroll
        for (int rt = 0; rt < 4; ++rt) {
            const int row = wr + rt * 16 + lq;
            const int sz = (row & 7) << 4;
            af[rt][0] = *(const bf16x8*)(AsB + row * 128 + ((lg * 16)      ^ sz));
            af[rt][1] = *(const bf16x8*)(AsB + row * 128 + ((64 + lg * 16) ^ sz));
        }
#pragma unroll
        for (int ct = 0; ct < 4; ++ct) {
            const int row = wc + ct * 16 + lq;
            const int sz = (row & 7) << 4;
            bfr[ct][0] = *(const bf16x8*)(BsB + row * 128 + ((lg * 16)      ^ sz));
            bfr[ct][1] = *(const bf16x8*)(BsB + row * 128 + ((64 + lg * 16) ^ sz));
        }
#pragma unroll
        for (int rt = 0; rt < 4; ++rt)
#pragma unroll
            for (int ct = 0; ct < 4; ++ct) {
                acc[rt][ct] = __builtin_amdgcn_mfma_f32_16x16x32_bf16(af[rt][0], bfr[ct][0], acc[rt][ct], 0, 0, 0);
                acc[rt][ct] = __builtin_amdgcn_mfma_f32_16x16x32_bf16(af[rt][1], bfr[ct][1], acc[rt][ct], 0, 0, 0);
            }
    }

#pragma unroll
    for (int rt = 0; rt < 4; ++rt)
#pragma unroll
        for (int ct = 0; ct < 4; ++ct) {
            const int row = bm + wr + rt * 16 + lg * 4;
            const int col = bn + wc + ct * 16 + lq;
            float scale = 1.f;
            if constexpr (QSCALE) scale = ((col % 192) < 64) ? QSCALE_LOG2E : 1.f;
#pragma unroll
            for (int r = 0; r < 4; ++r) {
                float vv = acc[rt][ct][r] * scale;
                if constexpr (OUT_BF16)
                    ((unsigned short*)Cv)[(size_t)(row + r) * N + col] = f2bf(vv);
                else
                    ((float*)Cv)[(size_t)(row + r) * N + col] = vv;
            }
        }
}

// ---------------------------------------------------------------------------
// 64x64 bf16 MFMA GEMM (known-good; output projection)
// ---------------------------------------------------------------------------
template <bool OUT_BF16, bool QSCALE>
__global__ __launch_bounds__(256)
void gemm_bt_mfma(const unsigned short* __restrict__ A,
                  const unsigned short* __restrict__ Bw,
                  void* __restrict__ Cv, int M, int N, int K) {
    __shared__ unsigned short As[64 * 64];
    __shared__ unsigned short Bs[64 * 64];
    char* const AsB = (char*)As;
    char* const BsB = (char*)Bs;
    const int tid  = threadIdx.x;
    const int lane = tid & 63;
    const int w    = tid >> 6;
    const int lg   = lane >> 4;
    const int lq   = lane & 15;
    const int bm = blockIdx.y * 64;
    const int bn = blockIdx.x * 64;
    const int wr = (w >> 1) * 32;
    const int wc = (w & 1) * 32;
    const int sr = tid >> 2;
    const int sc = (tid & 3) * 16;
    const int swzS = (sr & 7) << 4;

    f32x4 acc[2][2];
#pragma unroll
    for (int i = 0; i < 2; ++i)
#pragma unroll
        for (int j = 0; j < 2; ++j) acc[i][j] = (f32x4){0.f, 0.f, 0.f, 0.f};

    const unsigned short* ap = A  + (size_t)(bm + sr) * K + sc;
    const unsigned short* bp = Bw + (size_t)(bn + sr) * K + sc;

    for (int k0 = 0; k0 < K; k0 += 64) {
        __syncthreads();
        u16x8 av0 = *(const u16x8*)(ap + k0);
        u16x8 av1 = *(const u16x8*)(ap + k0 + 8);
        u16x8 bv0 = *(const u16x8*)(bp + k0);
        u16x8 bv1 = *(const u16x8*)(bp + k0 + 8);
        *(u16x8*)(AsB + sr * 128 + ((sc * 2)      ^ swzS)) = av0;
        *(u16x8*)(AsB + sr * 128 + ((sc * 2 + 16) ^ swzS)) = av1;
        *(u16x8*)(BsB + sr * 128 + ((sc * 2)      ^ swzS)) = bv0;
        *(u16x8*)(BsB + sr * 128 + ((sc * 2 + 16) ^ swzS)) = bv1;
        __syncthreads();

        bf16x8 af[2][2], bfr[2][2];
#pragma unroll
        for (int rt = 0; rt < 2; ++rt) {
            const int row = wr + rt * 16 + lq;
            const int sz = (row & 7) << 4;
            af[rt][0] = *(const bf16x8*)(AsB + row * 128 + ((lg * 16)      ^ sz));
            af[rt][1] = *(const bf16x8*)(AsB + row * 128 + ((64 + lg * 16) ^ sz));
        }
#pragma unroll
        for (int ct = 0; ct < 2; ++ct) {
            const int row = wc + ct * 16 + lq;
            const int sz = (row & 7) << 4;
            bfr[ct][0] = *(const bf16x8*)(BsB + row * 128 + ((lg * 16)      ^ sz));
            bfr[ct][1] = *(const bf16x8*)(BsB + row * 128 + ((64 + lg * 16) ^ sz));
        }
#pragma unroll
        for (int rt = 0; rt < 2; ++rt)
#pragma unroll
            for (int ct = 0; ct < 2; ++ct) {
                acc[rt][ct] = __builtin_amdgcn_mfma_f32_16x16x32_bf16(af[rt][0], bfr[ct][0], acc[rt][ct], 0, 0, 0);
                acc[rt][ct] = __builtin_amdgcn_mfma_f32_16x16x32_bf16(af[rt][1], bfr[ct][1], acc[rt][ct], 0, 0, 0);
            }
    }

#pragma unroll
    for (int rt = 0; rt < 2; ++rt)
#pragma unroll
        for (int ct = 0; ct < 2; ++ct) {
            const int row = bm + wr + rt * 16 + lg * 4;
            const int col = bn + wc + ct * 16 + lq;
            float scale = 1.f;
            if constexpr (QSCALE) scale = ((col % 192) < 64) ? QSCALE_LOG2E : 1.f;
#pragma unroll
            for (int r = 0; r < 4; ++r) {
                float vv = acc[rt][ct][r] * scale;
                if constexpr (OUT_BF16)
                    ((unsigned short*)Cv)[(size_t)(row + r) * N + col] = f2bf(vv);
                else
                    ((float*)Cv)[(size_t)(row + r) * N + col] = vv;
            }
        }
}

// ---------------------------------------------------------------------------
// Flash attention v7: v6 + counted-vmcnt pipeline (T4).
// K prefetch depth 2 (3 buffers, global_load_lds); V depth 1 (2 buffers,
// reg-staged T14). Per round: issue V(t+1) reg loads FIRST, then K(t+2)
// gloads -> the compiler's auto-wait for the V regs retires K(t+1) but
// leaves K(t+2) in flight (natural vmcnt(2)). Barrier = lgkmcnt(0) +
// raw s_barrier (NO vmcnt drain). No-max softmax as v6.
// ---------------------------------------------------------------------------
__global__ __launch_bounds__(256)
void attn_v7(const unsigned short* __restrict__ qkv, const int* __restrict__ mask,
             unsigned short* __restrict__ vout) {
    __shared__ __align__(16) char KsP[3][8192];
    __shared__ __align__(16) char VtP[2][8192];
    __shared__ __align__(16) float BiasF[S_LEN];

    const int tid  = threadIdx.x;
    const int lane = tid & 63;
    const int w    = tid >> 6;
    const int ln   = lane & 31;
    const int hi   = lane >> 5;
    const int q0 = blockIdx.x * 128;
    const int h  = blockIdx.y;
    const int b  = blockIdx.z;
    const size_t baseBH = (size_t)b * S_LEN * QKV_LD + (size_t)h * (3 * D_DIM);
    const unsigned short* const kv = qkv + baseBH;

    // ---- stage full bias row once: 2048 floats, 256 threads x 8 ----
    {
        const int4* mr = (const int4*)(mask + (size_t)b * S_LEN);
        int4 m0 = mr[tid * 2];
        int4 m1 = mr[tid * 2 + 1];
        float4 f0 = { m0.x ? 0.f : -30000.f, m0.y ? 0.f : -30000.f,
                      m0.z ? 0.f : -30000.f, m0.w ? 0.f : -30000.f };
        float4 f1 = { m1.x ? 0.f : -30000.f, m1.y ? 0.f : -30000.f,
                      m1.z ? 0.f : -30000.f, m1.w ? 0.f : -30000.f };
        ((float4*)BiasF)[tid * 2]     = f0;
        ((float4*)BiasF)[tid * 2 + 1] = f1;
    }

    // Q as B-frags (pre-scaled by 0.125*log2e): qf[kk] = Q[q=ln][d=kk*16+hi*8+j]
    bf16x8 qf[4];
    {
        const unsigned short* qp = kv + (size_t)(q0 + w * 32 + ln) * QKV_LD + hi * 8;
#pragma unroll
        for (int kk = 0; kk < 4; ++kk)
            qf[kk] = *(const bf16x8*)(qp + kk * 16);
    }

    const int lrow8 = lane >> 3;
    const int gblk  = (lane & 7) ^ lrow8;   // pre-swizzled 16B block for K stage
    const int vkb = (tid & 15) * 4;         // V staging key base
    const int vdb = (tid >> 4) * 4;         // V staging d base

    // ---- prologue: K(0)->buf0, K(1)->buf1, V(0)->buf0; full drain ----
    {
#pragma unroll
        for (int t = 0; t < 2; ++t) {
            const int c = w * 2 + t;
            gload16(kv + (size_t)(c * 8 + lrow8) * QKV_LD + D_DIM + gblk * 8,
                    KsP[0] + c * 1024);
            gload16(kv + (size_t)(64 + c * 8 + lrow8) * QKV_LD + D_DIM + gblk * 8,
                    KsP[1] + c * 1024);
        }
        u16x4 vr[4];
#pragma unroll
        for (int i = 0; i < 4; ++i)
            vr[i] = *(const u16x4*)(kv + (size_t)(vkb + i) * QKV_LD + 2 * D_DIM + vdb);
#pragma unroll
        for (int j = 0; j < 4; ++j) {
            u16x4 o = { vr[0][j], vr[1][j], vr[2][j], vr[3][j] };
            const int row = vdb + j;
            *(u16x4*)(VtP[0] + row * 128 + ((vkb * 2) ^ ((row & 7) << 4))) = o;
        }
    }
    __builtin_amdgcn_sched_barrier(0);
    asm volatile("s_waitcnt vmcnt(0) lgkmcnt(0)" ::: "memory");
    __builtin_amdgcn_s_barrier();
    __builtin_amdgcn_sched_barrier(0);

    f32x16 accO[2];
#pragma unroll
    for (int dt = 0; dt < 2; ++dt)
#pragma unroll
        for (int r = 0; r < 16; ++r) accO[dt][r] = 0.f;
    f32x4 rsumv = (f32x4){0.f, 0.f, 0.f, 0.f};

    const int NT = S_LEN / 64;   // 32
    int cur3 = 0;                // t % 3
    int k2b  = 2;                // (t+2) % 3
    for (int it = 0; it < NT; ++it) {
        const int curv = it & 1;
        const int kv0 = it * 64;
        char* const KsC = KsP[cur3];
        char* const VtC = VtP[curv];
        const bool pfV = (it + 1 < NT);
        const bool pfK = (it + 2 < NT);

        // ---- issue V(t+1) reg loads FIRST (so their wait leaves K(t+2) in flight)
        u16x4 vr[4];
        if (pfV) {
            const int kvn = kv0 + 64;
#pragma unroll
            for (int i = 0; i < 4; ++i)
                vr[i] = *(const u16x4*)(kv + (size_t)(kvn + vkb + i) * QKV_LD + 2 * D_DIM + vdb);
        }
        // ---- then issue K(t+2) global_load_lds ----
        if (pfK) {
            const int kvn2 = kv0 + 128;
#pragma unroll
            for (int t = 0; t < 2; ++t) {
                const int c = w * 2 + t;
                gload16(kv + (size_t)(kvn2 + c * 8 + lrow8) * QKV_LD + D_DIM + gblk * 8,
                        KsP[k2b] + c * 1024);
            }
        }

        // ---- S^T = K Q^T + bias (log2 domain) ----
        f32x16 s[2];
#pragma unroll
        for (int ks = 0; ks < 2; ++ks)
#pragma unroll
            for (int m = 0; m < 4; ++m) {
                f32x4 b4 = *(const f32x4*)(&BiasF[kv0 + ks * 32 + m * 8 + hi * 4]);
#pragma unroll
                for (int i = 0; i < 4; ++i) s[ks][m * 4 + i] = b4[i];
            }
        __builtin_amdgcn_s_setprio(1);
#pragma unroll
        for (int ks = 0; ks < 2; ++ks) {
            const int krow = ks * 32 + ln;
            const int swz = (ln & 7) << 4;
#pragma unroll
            for (int kk = 0; kk < 4; ++kk) {
                bf16x8 kf = *(const bf16x8*)(KsC + krow * 128 + (((kk * 16 + hi * 8) * 2) ^ swz));
                s[ks] = __builtin_amdgcn_mfma_f32_32x32x16_bf16(kf, qf[kk], s[ks], 0, 0, 0);
            }
        }
        __builtin_amdgcn_s_setprio(0);

        // ---- p = exp2(s); 4 independent row-sum accumulators ----
#pragma unroll
        for (int ks = 0; ks < 2; ++ks)
#pragma unroll
            for (int r = 0; r < 16; ++r) {
                float p = __builtin_amdgcn_exp2f(s[ks][r]);
                s[ks][r] = p;
                rsumv[r & 3] += p;
            }

        // ---- assemble P^T B-frags in-register ----
        bf16x8 pb[4];
#pragma unroll
        for (int ks = 0; ks < 2; ++ks) {
            unsigned wA[4], wB[4];
#pragma unroll
            for (int m = 0; m < 4; ++m) {
                wA[m] = cvtpk_bf16(s[ks][4 * m + 0], s[ks][4 * m + 1]);
                wB[m] = cvtpk_bf16(s[ks][4 * m + 2], s[ks][4 * m + 3]);
            }
#pragma unroll
            for (int t = 0; t < 2; ++t) {
                i32x2 ra = __builtin_amdgcn_permlane32_swap((int)wA[2 * t], (int)wA[2 * t + 1], false, false);
                i32x2 rb = __builtin_amdgcn_permlane32_swap((int)wB[2 * t], (int)wB[2 * t + 1], false, false);
                union { unsigned u[4]; bf16x8 v; } uu;
                uu.u[0] = (unsigned)ra[0];
                uu.u[1] = (unsigned)rb[0];
                uu.u[2] = (unsigned)ra[1];
                uu.u[3] = (unsigned)rb[1];
                pb[ks * 2 + t] = uu.v;
            }
        }

        // ---- O^T += V^T P^T ----
        __builtin_amdgcn_s_setprio(1);
#pragma unroll
        for (int dt = 0; dt < 2; ++dt) {
            const int drow = dt * 32 + ln;
            const int swz = (ln & 7) << 4;
#pragma unroll
            for (int n = 0; n < 4; ++n) {
                bf16x8 va = *(const bf16x8*)(VtC + drow * 128 + (((n * 16 + hi * 8) * 2) ^ swz));
                accO[dt] = __builtin_amdgcn_mfma_f32_32x32x16_bf16(va, pb[n], accO[dt], 0, 0, 0);
            }
        }
        __builtin_amdgcn_s_setprio(0);

        // ---- complete V prefetch: regs -> LDS (compiler auto-waits the
        //      V-reg loads; K(t+2) gloads stay in flight) ----
        if (pfV) {
#pragma unroll
            for (int j = 0; j < 4; ++j) {
                u16x4 o = { vr[0][j], vr[1][j], vr[2][j], vr[3][j] };
                const int row = vdb + j;
                *(u16x4*)(VtP[curv ^ 1] + row * 128 + ((vkb * 2) ^ ((row & 7) << 4))) = o;
            }
            // barrier WITHOUT vmcnt drain: LDS writes flushed, K loads fly on
            __builtin_amdgcn_sched_barrier(0);
            asm volatile("s_waitcnt lgkmcnt(0)" ::: "memory");
            __builtin_amdgcn_s_barrier();
            __builtin_amdgcn_sched_barrier(0);
        }

        cur3 = (cur3 == 2) ? 0 : cur3 + 1;
        k2b  = (k2b  == 2) ? 0 : k2b  + 1;
    }

    // ---- epilogue: one partner-reduce of the row sum, normalize, store ----
    float rsum = rsumv[0] + rsumv[1] + rsumv[2] + rsumv[3];
    {
        i32x2 rr = __builtin_amdgcn_permlane32_swap(__float_as_int(rsum), __float_as_int(rsum), false, false);
        rsum = __int_as_float(rr[0]) + __int_as_float(rr[1]);
    }
    const float inv = 1.f / rsum;
    unsigned short* op = vout + (size_t)(b * S_LEN + q0 + w * 32 + ln) * E_DIM + h * D_DIM;
#pragma unroll
    for (int dt = 0; dt < 2; ++dt)
#pragma unroll
        for (int m = 0; m < 4; ++m) {
            u16x4 o;
#pragma unroll
            for (int i = 0; i < 4; ++i) o[i] = f2bf(accO[dt][4 * m + i] * inv);
            *(u16x4*)(op + dt * 32 + m * 8 + hi * 4) = o;
        }
}

// ---------------------------------------------------------------------------
extern "C" void kernel_launch(void* const* d_in, const int* in_sizes, int n_in,
                              void* d_out, int out_size, void* d_ws, size_t ws_size,
                              hipStream_t stream) {
    const float* x      = (const float*)d_in[0];
    const int*   mask   = (const int*)d_in[1];
    const float* w_qkv  = (const float*)d_in[2];
    const float* w_o    = (const float*)d_in[3];
    float*       out    = (float*)d_out;

    const int M = B_NUM * S_LEN;     // 4096
    unsigned short* qkvb = (unsigned short*)d_ws;                    // M x 3E
    unsigned short* vbuf = qkvb + (size_t)M * 3 * E_DIM;             // M x E
    unsigned short* xb   = vbuf + (size_t)M * E_DIM;                 // M x E
    unsigned short* wqb  = xb   + (size_t)M * E_DIM;                 // 3E x E
    unsigned short* wob  = wqb  + (size_t)3 * E_DIM * E_DIM;         // E x E

    dim3 blk(256);
    {
        int n4;
        n4 = M * E_DIM / 4;
        cvt_f32_bf16<<<dim3((n4 + 255) / 256), blk, 0, stream>>>(x, xb, n4);
        n4 = 3 * E_DIM * E_DIM / 4;
        cvt_f32_bf16<<<dim3((n4 + 255) / 256), blk, 0, stream>>>(w_qkv, wqb, n4);
        n4 = E_DIM * E_DIM / 4;
        cvt_f32_bf16<<<dim3((n4 + 255) / 256), blk, 0, stream>>>(w_o, wob, n4);
    }

    // QKV projection (q columns pre-scaled by 0.125*log2e), bf16 out
    gemm_bt_mfma128<true, true><<<dim3(3 * E_DIM / 128, M / 128), blk, 0, stream>>>(
        xb, wqb, qkvb, M, 3 * E_DIM, E_DIM);

    // flash attention v7 (counted-vmcnt pipeline)
    attn_v7<<<dim3(S_LEN / 128, H_NUM, B_NUM), blk, 0, stream>>>(qkvb, mask, vbuf);

    // output projection, fp32 out
    gemm_bt_mfma<false, false><<<dim3(E_DIM / 64, M / 64), blk, 0, stream>>>(
        vbuf, wob, out, M, E_DIM, E_DIM);
}